// Round 5
// baseline (160.727 us; speedup 1.0000x reference)
//
#include <hip/hip_runtime.h>

typedef __bf16 bf16x8 __attribute__((ext_vector_type(8)));
typedef float  f32x4  __attribute__((ext_vector_type(4)));

// Sizes: B=64, C=128, ORI=6, HW=784, NB=4, BS=32
// xh strides (floats): b:1204224, c:9408, ori:1568, hw:2, ri:1

static __device__ __forceinline__ unsigned short bf16bits(float f) {
  __bf16 h = (__bf16)f; return __builtin_bit_cast(unsigned short, h);
}
static __device__ __forceinline__ unsigned int pack2(float a, float b) {
  return (unsigned int)bf16bits(a) | ((unsigned int)bf16bits(b) << 16);
}

// ---------------- weight prep: combined real matrix, transposed [n][k], bf16, PLAIN layout:
// wg[nb*8192 + layer*4096 + n*64 + k]
//  n<32,k<32:  wr[k][n]    n<32,k>=32: -wi[k-32][n]
//  n>=32,k<32: wi[k][n-32] n>=32,k>=32: wr[k-32][n-32]
__global__ void prep_weights(const float* __restrict__ w1, const float* __restrict__ w2,
                             unsigned short* __restrict__ wg) {
  const int e = blockIdx.x * 256 + threadIdx.x;      // 0..32767 = nb|layer|n|k
  const int nb    = e >> 13;
  const int layer = (e >> 12) & 1;
  const int n = (e >> 6) & 63;
  const int k = e & 63;
  const float* w = layer ? w2 : w1;
  const int kk = k & 31, nn = n & 31;
  float v;
  if (n < 32) {
    v = (k < 32) ?  w[((0 * 4 + nb) * 32 + kk) * 32 + nn]
                 : -w[((1 * 4 + nb) * 32 + kk) * 32 + nn];
  } else {
    v = (k < 32) ?  w[((1 * 4 + nb) * 32 + kk) * 32 + nn]
                 :  w[((0 * 4 + nb) * 32 + kk) * 32 + nn];
  }
  wg[e] = bf16bits(v);
}

// ---------------- fused main kernel, ZERO barriers ----------------
// grid = 6272: (bi&3)==3 -> lowpass block (1568); else xh block (4704)
__global__ __launch_bounds__(256, 3)
void fused_kernel(const float* __restrict__ xh, const unsigned short* __restrict__ wg,
                  const float* __restrict__ b1, const float* __restrict__ b2,
                  const float* __restrict__ xl, const float* __restrict__ wll,
                  float* __restrict__ out) {
  __shared__ __align__(16) unsigned short Xs[256 * 64];   // X tile -> H tile (bf16), 32KB only

  const int t = threadIdx.x;
  const int bi = blockIdx.x;

  if ((bi & 3) == 3) {                    // ---- lowpass path: xl_out = xl * w_ll ----
    const int llb = bi >> 2;              // 0..1567, 1024 float4 each
    const float4* xi4 = reinterpret_cast<const float4*>(xl);
    const float4* w4  = reinterpret_cast<const float4*>(wll);
    float4* o4 = reinterpret_cast<float4*>(out);
#pragma unroll
    for (int j = 0; j < 4; ++j) {
      const int i = llb * 1024 + j * 256 + t;
      const float4 x = xi4[i];
      const float4 w = w4[i % 25088];
      float4 r; r.x = x.x * w.x; r.y = x.y * w.y; r.z = x.z * w.z; r.w = x.w * w.w;
      o4[i] = r;
    }
    return;
  }

  const int xi = (bi >> 2) * 3 + (bi & 3);   // 0..4703
  const int mt  = xi % 196;
  const int snb = xi / 196;
  const int ori = snb >> 2;
  const int nb  = snb & 3;
  const int p0 = mt << 8;

  const int lane = t & 63;
  const int wv = t >> 6;
  const int lr = lane & 15;
  const int lg = lane >> 4;

  char* XB = reinterpret_cast<char*>(Xs);
  const float* xb = xh + (size_t)(nb * 32) * 9408 + ori * 1568;
  float* ob = out + 6422528 + (size_t)(nb * 32) * 9408 + ori * 1568;
  const unsigned short* wbase = wg + nb * 8192;

  // ================= ISSUE: X loads + layer-1 W fragments + layer-1 bias =================
  f32x4 R[16];
  const int lr16 = t & 15;
  const int cg   = (t >> 4) & 3;
  const int wvi  = t >> 6;
#pragma unroll
  for (int j = 0; j < 8; ++j) {
    const int c = 2 * cg + 8 * (j >> 1);               // even channel of pair
    const int p = 2 * lr16 + 32 * (wvi * 2 + (j & 1)); // even local pos, wave-private range
    const int P = p0 + p;
    const int bb = P / 784;
    const int hw = P - bb * 784;
    const float* s = xb + (size_t)bb * 1204224 + c * 9408 + hw * 2;
    R[2 * j]     = *reinterpret_cast<const f32x4*>(s);          // ch c : re,im,re,im
    R[2 * j + 1] = *reinterpret_cast<const f32x4*>(s + 9408);   // ch c+1
  }
  bf16x8 wf1[4][2];                        // layer-1 W fragments, direct from global (L2-hot)
#pragma unroll
  for (int mi = 0; mi < 4; ++mi)
#pragma unroll
    for (int ks = 0; ks < 2; ++ks)
      wf1[mi][ks] = *reinterpret_cast<const bf16x8*>(wbase + (mi * 16 + lr) * 64 + (ks * 4 + lg) * 8);
  f32x4 bv1[4];                            // layer-1 bias vectors (broadcast within group)
#pragma unroll
  for (int mi = 0; mi < 4; ++mi)
    bv1[mi] = *reinterpret_cast<const f32x4*>(b1 + (mi >> 1) * 128 + nb * 32 + (mi & 1) * 16 + lg * 4);
  __builtin_amdgcn_sched_barrier(0);       // keep all loads above the LDS writes

  // ================= pack X -> wave-private LDS slice (no barrier needed) =================
#pragma unroll
  for (int j = 0; j < 8; ++j) {
    const int c = 2 * cg + 8 * (j >> 1);
    const int p = 2 * lr16 + 32 * (wvi * 2 + (j & 1));
    const int g0 = c >> 3;
    const int off = (c & 7) * 2;
    const int s0 = (p >> 1) & 7;
    const f32x4 vA = R[2 * j], vB = R[2 * j + 1];
    *reinterpret_cast<unsigned int*>(XB + p * 128 + ((g0 ^ s0) * 16) + off)             = pack2(vA[0], vB[0]);
    *reinterpret_cast<unsigned int*>(XB + p * 128 + (((g0 + 4) ^ s0) * 16) + off)       = pack2(vA[1], vB[1]);
    *reinterpret_cast<unsigned int*>(XB + (p + 1) * 128 + ((g0 ^ s0) * 16) + off)       = pack2(vA[2], vB[2]);
    *reinterpret_cast<unsigned int*>(XB + (p + 1) * 128 + (((g0 + 4) ^ s0) * 16) + off) = pack2(vA[3], vB[3]);
  }

  // ---- layer 1: D1[n][p] = W1t * X^T (all LDS reads wave-private) ----
  f32x4 acc[4][4];
#pragma unroll
  for (int mi = 0; mi < 4; ++mi)
#pragma unroll
    for (int ni = 0; ni < 4; ++ni)
      acc[mi][ni] = (f32x4){0.f, 0.f, 0.f, 0.f};

#pragma unroll
  for (int ks = 0; ks < 2; ++ks) {
    bf16x8 xf[4];
#pragma unroll
    for (int ni = 0; ni < 4; ++ni) {
      const int p = wv * 64 + ni * 16 + lr;
      xf[ni] = *reinterpret_cast<const bf16x8*>(XB + p * 128 + (((ks * 4 + lg) ^ ((p >> 1) & 7)) * 16));
    }
#pragma unroll
    for (int mi = 0; mi < 4; ++mi)
#pragma unroll
      for (int ni = 0; ni < 4; ++ni)
        acc[mi][ni] = __builtin_amdgcn_mfma_f32_16x16x32_bf16(wf1[mi][ks], xf[ni], acc[mi][ni], 0, 0, 0);
  }

  // ---- issue layer-2 W fragments + biases (hide under ep1 + L2 fragment reads) ----
  bf16x8 wf2[4][2];
#pragma unroll
  for (int mi = 0; mi < 4; ++mi)
#pragma unroll
    for (int ks = 0; ks < 2; ++ks)
      wf2[mi][ks] = *reinterpret_cast<const bf16x8*>(wbase + 4096 + (mi * 16 + lr) * 64 + (ks * 4 + lg) * 8);
  f32x4 bre2[2], bim2[2];
#pragma unroll
  for (int mi = 0; mi < 2; ++mi) {
    bre2[mi] = *reinterpret_cast<const f32x4*>(b2 + nb * 32 + mi * 16 + lg * 4);
    bim2[mi] = *reinterpret_cast<const f32x4*>(b2 + 128 + nb * 32 + mi * 16 + lg * 4);
  }

  // ---- ep1: H = relu(D1 + b1) -> back into wave-private Xs rows ----
#pragma unroll
  for (int mi = 0; mi < 4; ++mi) {
    const int gH = mi * 2 + (lg >> 1);
    const int offH = (lg & 1) * 8;
#pragma unroll
    for (int ni = 0; ni < 4; ++ni) {
      const int p = wv * 64 + ni * 16 + lr;
      const float h0 = fmaxf(acc[mi][ni][0] + bv1[mi][0], 0.f);
      const float h1 = fmaxf(acc[mi][ni][1] + bv1[mi][1], 0.f);
      const float h2 = fmaxf(acc[mi][ni][2] + bv1[mi][2], 0.f);
      const float h3 = fmaxf(acc[mi][ni][3] + bv1[mi][3], 0.f);
      uint2 u; u.x = pack2(h0, h1); u.y = pack2(h2, h3);
      *reinterpret_cast<uint2*>(XB + p * 128 + ((gH ^ ((p >> 1) & 7)) * 16) + offH) = u;
    }
  }

  // ---- layer 2: D2[n][p] = W2t * H^T (wave-private) ----
  f32x4 acc2[4][4];
#pragma unroll
  for (int mi = 0; mi < 4; ++mi)
#pragma unroll
    for (int ni = 0; ni < 4; ++ni)
      acc2[mi][ni] = (f32x4){0.f, 0.f, 0.f, 0.f};

#pragma unroll
  for (int ks = 0; ks < 2; ++ks) {
    bf16x8 hf[4];
#pragma unroll
    for (int ni = 0; ni < 4; ++ni) {
      const int p = wv * 64 + ni * 16 + lr;
      hf[ni] = *reinterpret_cast<const bf16x8*>(XB + p * 128 + (((ks * 4 + lg) ^ ((p >> 1) & 7)) * 16));
    }
#pragma unroll
    for (int mi = 0; mi < 4; ++mi)
#pragma unroll
      for (int ni = 0; ni < 4; ++ni)
        acc2[mi][ni] = __builtin_amdgcn_mfma_f32_16x16x32_bf16(wf2[mi][ks], hf[ni], acc2[mi][ni], 0, 0, 0);
  }

  // ---- ep2: out = D2 + b2, interleaved (re,im) float2 stores ----
#pragma unroll
  for (int ni = 0; ni < 4; ++ni) {
    const int p = wv * 64 + ni * 16 + lr;
    const int P = p0 + p;
    const int bb = P / 784;
    const int hw = P - bb * 784;
    float* obase = ob + (size_t)bb * 1204224 + hw * 2;
#pragma unroll
    for (int mi = 0; mi < 2; ++mi) {
#pragma unroll
      for (int j = 0; j < 4; ++j) {
        const int c = mi * 16 + lg * 4 + j;
        float2 v;
        v.x = acc2[mi][ni][j] + bre2[mi][j];
        v.y = acc2[mi + 2][ni][j] + bim2[mi][j];
        *reinterpret_cast<float2*>(obase + (size_t)c * 9408) = v;
      }
    }
  }
}

extern "C" void kernel_launch(void* const* d_in, const int* in_sizes, int n_in,
                              void* d_out, int out_size, void* d_ws, size_t ws_size,
                              hipStream_t stream) {
  (void)in_sizes; (void)n_in; (void)out_size; (void)ws_size;
  const float* xl  = (const float*)d_in[0];
  const float* xh  = (const float*)d_in[1];
  const float* wll = (const float*)d_in[2];
  const float* w1  = (const float*)d_in[3];
  const float* w2  = (const float*)d_in[4];
  const float* b1  = (const float*)d_in[5];
  const float* b2  = (const float*)d_in[6];
  float* out = (float*)d_out;
  unsigned short* wg = (unsigned short*)d_ws;   // 65536 bytes used

  prep_weights<<<128, 256, 0, stream>>>(w1, w2, wg);
  fused_kernel<<<6272, 256, 0, stream>>>(xh, wg, b1, b2, xl, wll, out);
}

// Round 6
// 155.617 us; speedup vs baseline: 1.0328x; 1.0328x over previous
//
#include <hip/hip_runtime.h>

typedef __bf16 bf16x8 __attribute__((ext_vector_type(8)));
typedef float  f32x4  __attribute__((ext_vector_type(4)));

// Sizes: B=64, C=128, ORI=6, HW=784, NB=4, BS=32
// xh strides (floats): b:1204224, c:9408, ori:1568, hw:2, ri:1

static __device__ __forceinline__ unsigned short bf16bits(float f) {
  __bf16 h = (__bf16)f; return __builtin_bit_cast(unsigned short, h);
}
static __device__ __forceinline__ unsigned int pack2(float a, float b) {
  return (unsigned int)bf16bits(a) | ((unsigned int)bf16bits(b) << 16);
}

// ---------------- weight prep: combined real matrix, transposed [n][k], bf16,
// written as the PRE-SWIZZLED LDS image so the main kernel does a linear copy.
__global__ void prep_weights(const float* __restrict__ w1, const float* __restrict__ w2,
                             unsigned short* __restrict__ wg) {
  const int e = blockIdx.x * 256 + threadIdx.x;      // 0..32767
  const int nb    = e >> 13;
  const int layer = (e >> 12) & 1;
  const int n = (e >> 6) & 63;
  const int k = e & 63;
  const float* w = layer ? w2 : w1;
  const int kk = k & 31, nn = n & 31;
  float v;
  if (n < 32) {
    v = (k < 32) ?  w[((0 * 4 + nb) * 32 + kk) * 32 + nn]
                 : -w[((1 * 4 + nb) * 32 + kk) * 32 + nn];
  } else {
    v = (k < 32) ?  w[((1 * 4 + nb) * 32 + kk) * 32 + nn]
                 :  w[((0 * 4 + nb) * 32 + kk) * 32 + nn];
  }
  const int pos = nb * 8192 + layer * 4096 + n * 64 + (((k >> 3) ^ ((n >> 1) & 7)) * 8) + (k & 7);
  wg[pos] = bf16bits(v);
}

// ---------------- fused main kernel: 4 tiles per xh block, wave-level pipeline ----------------
// grid = 1568: (bi&3)==3 -> lowpass block (392); else xh block (1176): (ori, nb, 4-tile group)
__global__ __launch_bounds__(256, 2)
void fused_kernel(const float* __restrict__ xh, const unsigned short* __restrict__ wg,
                  const float* __restrict__ b1, const float* __restrict__ b2,
                  const float* __restrict__ xl, const float* __restrict__ wll,
                  float* __restrict__ out) {
  __shared__ __align__(16) unsigned short Xs[256 * 64];   // X/H tile (bf16), wave-private quarters
  __shared__ __align__(16) unsigned short Ws[2 * 64 * 64];// pre-swizzled weight image

  const int t = threadIdx.x;
  const int bi = blockIdx.x;

  if ((bi & 3) == 3) {                    // ---- lowpass path: xl_out = xl * w_ll ----
    const int llb = bi >> 2;              // 0..391, 4096 float4 each
    const float4* xi4 = reinterpret_cast<const float4*>(xl);
    const float4* w4  = reinterpret_cast<const float4*>(wll);
    float4* o4 = reinterpret_cast<float4*>(out);
#pragma unroll
    for (int jj = 0; jj < 4; ++jj) {
      float4 x[4], w[4];
#pragma unroll
      for (int j = 0; j < 4; ++j) {
        const int i = llb * 4096 + (jj * 4 + j) * 256 + t;
        x[j] = xi4[i];
        w[j] = w4[i % 25088];
      }
#pragma unroll
      for (int j = 0; j < 4; ++j) {
        const int i = llb * 4096 + (jj * 4 + j) * 256 + t;
        float4 r; r.x = x[j].x * w[j].x; r.y = x[j].y * w[j].y;
        r.z = x[j].z * w[j].z; r.w = x[j].w * w[j].w;
        o4[i] = r;
      }
    }
    return;
  }

  const int xi = (bi >> 2) * 3 + (bi & 3);   // 0..1175
  const int tg  = xi % 49;
  const int snb = xi / 49;
  const int ori = snb >> 2;
  const int nb  = snb & 3;
  const int p00 = tg << 10;                  // 4 tiles * 256 positions

  const int lane = t & 63;
  const int wv = t >> 6;
  const int lr = lane & 15;
  const int lg = lane >> 4;
  const int lr16 = t & 15;
  const int cg   = (t >> 4) & 3;

  char* XB = reinterpret_cast<char*>(Xs);
  const char* WB = reinterpret_cast<const char*>(Ws);
  const float* xb = xh + (size_t)(nb * 32) * 9408 + ori * 1568;
  float* ob = out + 6422528 + (size_t)(nb * 32) * 9408 + ori * 1568;

  f32x4 R[16];                               // single staging buffer, reused across tiles

  auto issueX = [&](int p0) {
#pragma unroll
    for (int j = 0; j < 8; ++j) {
      const int c = 2 * cg + 8 * (j >> 1);             // even channel of pair
      const int p = 2 * lr16 + 32 * (wv * 2 + (j & 1)); // even wave-private position
      const int P = p0 + p;
      const int bb = P / 784;
      const int hw = P - bb * 784;
      const float* s = xb + (size_t)bb * 1204224 + c * 9408 + hw * 2;
      R[2 * j]     = *reinterpret_cast<const f32x4*>(s);          // ch c : re,im,re,im
      R[2 * j + 1] = *reinterpret_cast<const f32x4*>(s + 9408);   // ch c+1
    }
  };
  auto packX = [&]() {
#pragma unroll
    for (int j = 0; j < 8; ++j) {
      const int c = 2 * cg + 8 * (j >> 1);
      const int p = 2 * lr16 + 32 * (wv * 2 + (j & 1));
      const int g0 = c >> 3;
      const int off = (c & 7) * 2;
      const int s0 = (p >> 1) & 7;
      const f32x4 vA = R[2 * j], vB = R[2 * j + 1];
      *reinterpret_cast<unsigned int*>(XB + p * 128 + ((g0 ^ s0) * 16) + off)             = pack2(vA[0], vB[0]);
      *reinterpret_cast<unsigned int*>(XB + p * 128 + (((g0 + 4) ^ s0) * 16) + off)       = pack2(vA[1], vB[1]);
      *reinterpret_cast<unsigned int*>(XB + (p + 1) * 128 + ((g0 ^ s0) * 16) + off)       = pack2(vA[2], vB[2]);
      *reinterpret_cast<unsigned int*>(XB + (p + 1) * 128 + (((g0 + 4) ^ s0) * 16) + off) = pack2(vA[3], vB[3]);
    }
  };

  // ---- prologue: issue tile-0 X loads, stage weights, load biases ----
  issueX(p00);
  {
    const uint4* src = reinterpret_cast<const uint4*>(wg + nb * 8192);
    uint4* dst = reinterpret_cast<uint4*>(Ws);
#pragma unroll
    for (int it = 0; it < 4; ++it) dst[it * 256 + t] = src[it * 256 + t];
  }
  f32x4 bv1[4];
#pragma unroll
  for (int mi = 0; mi < 4; ++mi)
    bv1[mi] = *reinterpret_cast<const f32x4*>(b1 + (mi >> 1) * 128 + nb * 32 + (mi & 1) * 16 + lg * 4);
  f32x4 bre2[2], bim2[2];
#pragma unroll
  for (int mi = 0; mi < 2; ++mi) {
    bre2[mi] = *reinterpret_cast<const f32x4*>(b2 + nb * 32 + mi * 16 + lg * 4);
    bim2[mi] = *reinterpret_cast<const f32x4*>(b2 + 128 + nb * 32 + mi * 16 + lg * 4);
  }
  __syncthreads();                           // weights visible (drains prologue loads too)

#pragma unroll
  for (int tt = 0; tt < 4; ++tt) {
    const int p0 = p00 + tt * 256;

    packX();                                 // consume R (tile tt)
    if (tt < 3) issueX(p0 + 256);            // tile tt+1 loads fly under compute+stores
    __builtin_amdgcn_sched_barrier(0);       // pin the issue above all compute

    // ---- layer 1: D1[n][p] = W1t * X^T (wave-private LDS reads) ----
    f32x4 acc[4][4];
#pragma unroll
    for (int mi = 0; mi < 4; ++mi)
#pragma unroll
      for (int ni = 0; ni < 4; ++ni)
        acc[mi][ni] = (f32x4){0.f, 0.f, 0.f, 0.f};

#pragma unroll
    for (int ks = 0; ks < 2; ++ks) {
      bf16x8 wf[4], xf[4];
#pragma unroll
      for (int mi = 0; mi < 4; ++mi) {
        const int n = mi * 16 + lr;
        wf[mi] = *reinterpret_cast<const bf16x8*>(WB + n * 128 + (((ks * 4 + lg) ^ ((n >> 1) & 7)) * 16));
      }
#pragma unroll
      for (int ni = 0; ni < 4; ++ni) {
        const int p = wv * 64 + ni * 16 + lr;
        xf[ni] = *reinterpret_cast<const bf16x8*>(XB + p * 128 + (((ks * 4 + lg) ^ ((p >> 1) & 7)) * 16));
      }
#pragma unroll
      for (int mi = 0; mi < 4; ++mi)
#pragma unroll
        for (int ni = 0; ni < 4; ++ni)
          acc[mi][ni] = __builtin_amdgcn_mfma_f32_16x16x32_bf16(wf[mi], xf[ni], acc[mi][ni], 0, 0, 0);
    }

    // ---- ep1: H = relu(D1 + b1) -> wave-private Xs rows ----
#pragma unroll
    for (int mi = 0; mi < 4; ++mi) {
      const int gH = mi * 2 + (lg >> 1);
      const int offH = (lg & 1) * 8;
#pragma unroll
      for (int ni = 0; ni < 4; ++ni) {
        const int p = wv * 64 + ni * 16 + lr;
        const float h0 = fmaxf(acc[mi][ni][0] + bv1[mi][0], 0.f);
        const float h1 = fmaxf(acc[mi][ni][1] + bv1[mi][1], 0.f);
        const float h2 = fmaxf(acc[mi][ni][2] + bv1[mi][2], 0.f);
        const float h3 = fmaxf(acc[mi][ni][3] + bv1[mi][3], 0.f);
        uint2 u; u.x = pack2(h0, h1); u.y = pack2(h2, h3);
        *reinterpret_cast<uint2*>(XB + p * 128 + ((gH ^ ((p >> 1) & 7)) * 16) + offH) = u;
      }
    }

    // ---- layer 2: D2[n][p] = W2t * H^T ----
    f32x4 acc2[4][4];
#pragma unroll
    for (int mi = 0; mi < 4; ++mi)
#pragma unroll
      for (int ni = 0; ni < 4; ++ni)
        acc2[mi][ni] = (f32x4){0.f, 0.f, 0.f, 0.f};

#pragma unroll
    for (int ks = 0; ks < 2; ++ks) {
      bf16x8 wf[4], hf[4];
#pragma unroll
      for (int mi = 0; mi < 4; ++mi) {
        const int n = mi * 16 + lr;
        wf[mi] = *reinterpret_cast<const bf16x8*>(WB + 8192 + n * 128 + (((ks * 4 + lg) ^ ((n >> 1) & 7)) * 16));
      }
#pragma unroll
      for (int ni = 0; ni < 4; ++ni) {
        const int p = wv * 64 + ni * 16 + lr;
        hf[ni] = *reinterpret_cast<const bf16x8*>(XB + p * 128 + (((ks * 4 + lg) ^ ((p >> 1) & 7)) * 16));
      }
#pragma unroll
      for (int mi = 0; mi < 4; ++mi)
#pragma unroll
        for (int ni = 0; ni < 4; ++ni)
          acc2[mi][ni] = __builtin_amdgcn_mfma_f32_16x16x32_bf16(wf[mi], hf[ni], acc2[mi][ni], 0, 0, 0);
    }

    // ---- ep2: out = D2 + b2, interleaved (re,im) float2 stores ----
#pragma unroll
    for (int ni = 0; ni < 4; ++ni) {
      const int p = wv * 64 + ni * 16 + lr;
      const int P = p0 + p;
      const int bb = P / 784;
      const int hw = P - bb * 784;
      float* obase = ob + (size_t)bb * 1204224 + hw * 2;
#pragma unroll
      for (int mi = 0; mi < 2; ++mi) {
#pragma unroll
        for (int j = 0; j < 4; ++j) {
          const int c = mi * 16 + lg * 4 + j;
          float2 v;
          v.x = acc2[mi][ni][j] + bre2[mi][j];
          v.y = acc2[mi + 2][ni][j] + bim2[mi][j];
          *reinterpret_cast<float2*>(obase + (size_t)c * 9408) = v;
        }
      }
    }
  }
}

extern "C" void kernel_launch(void* const* d_in, const int* in_sizes, int n_in,
                              void* d_out, int out_size, void* d_ws, size_t ws_size,
                              hipStream_t stream) {
  (void)in_sizes; (void)n_in; (void)out_size; (void)ws_size;
  const float* xl  = (const float*)d_in[0];
  const float* xh  = (const float*)d_in[1];
  const float* wll = (const float*)d_in[2];
  const float* w1  = (const float*)d_in[3];
  const float* w2  = (const float*)d_in[4];
  const float* b1  = (const float*)d_in[5];
  const float* b2  = (const float*)d_in[6];
  float* out = (float*)d_out;
  unsigned short* wg = (unsigned short*)d_ws;   // 65536 bytes used

  prep_weights<<<128, 256, 0, stream>>>(w1, w2, wg);
  fused_kernel<<<1568, 256, 0, stream>>>(xh, wg, b1, b2, xl, wll, out);
}

// Round 7
// 150.132 us; speedup vs baseline: 1.0706x; 1.0365x over previous
//
#include <hip/hip_runtime.h>

typedef __bf16 bf16x8 __attribute__((ext_vector_type(8)));
typedef float  f32x4  __attribute__((ext_vector_type(4)));

// Sizes: B=64, C=128, ORI=6, HW=784, NB=4, BS=32
// xh strides (floats): b:1204224, c:9408, ori:1568, hw:2, ri:1

static __device__ __forceinline__ unsigned short bf16bits(float f) {
  __bf16 h = (__bf16)f; return __builtin_bit_cast(unsigned short, h);
}
static __device__ __forceinline__ unsigned int pack2(float a, float b) {
  return (unsigned int)bf16bits(a) | ((unsigned int)bf16bits(b) << 16);
}

// ---------------- weight prep: combined real matrix, transposed [n][k], bf16,
// written as the PRE-SWIZZLED LDS image so the main kernel does a linear copy.
__global__ void prep_weights(const float* __restrict__ w1, const float* __restrict__ w2,
                             unsigned short* __restrict__ wg) {
  const int e = blockIdx.x * 256 + threadIdx.x;      // 0..32767
  const int nb    = e >> 13;
  const int layer = (e >> 12) & 1;
  const int n = (e >> 6) & 63;
  const int k = e & 63;
  const float* w = layer ? w2 : w1;
  const int kk = k & 31, nn = n & 31;
  float v;
  if (n < 32) {
    v = (k < 32) ?  w[((0 * 4 + nb) * 32 + kk) * 32 + nn]
                 : -w[((1 * 4 + nb) * 32 + kk) * 32 + nn];
  } else {
    v = (k < 32) ?  w[((1 * 4 + nb) * 32 + kk) * 32 + nn]
                 :  w[((0 * 4 + nb) * 32 + kk) * 32 + nn];
  }
  const int pos = nb * 8192 + layer * 4096 + n * 64 + (((k >> 3) ^ ((n >> 1) & 7)) * 8) + (k & 7);
  wg[pos] = bf16bits(v);
}

// ---------------- fused main kernel ----------------
// grid = 6272: (bi&3)==3 -> lowpass block (1568); else xh block (4704)
// xh reads are channel-major: each vmem instruction = 64 consecutive positions
// of ONE channel = a single contiguous 512B segment.
__global__ __launch_bounds__(256, 3)
void fused_kernel(const float* __restrict__ xh, const unsigned short* __restrict__ wg,
                  const float* __restrict__ b1, const float* __restrict__ b2,
                  const float* __restrict__ xl, const float* __restrict__ wll,
                  float* __restrict__ out) {
  __shared__ __align__(16) unsigned short Xs[256 * 64];   // X tile -> H tile (bf16), 32KB
  __shared__ __align__(16) unsigned short Ws[2 * 64 * 64];// 16KB pre-swizzled weight image
  __shared__ __align__(16) float Bs[128];

  const int t = threadIdx.x;
  const int bi = blockIdx.x;

  if ((bi & 3) == 3) {                    // ---- lowpass path: xl_out = xl * w_ll ----
    const int llb = bi >> 2;              // 0..1567, 1024 float4 each
    const float4* xi4 = reinterpret_cast<const float4*>(xl);
    const float4* w4  = reinterpret_cast<const float4*>(wll);
    float4* o4 = reinterpret_cast<float4*>(out);
#pragma unroll
    for (int j = 0; j < 4; ++j) {
      const int i = llb * 1024 + j * 256 + t;
      const float4 x = xi4[i];
      const float4 w = w4[i % 25088];
      float4 r; r.x = x.x * w.x; r.y = x.y * w.y; r.z = x.z * w.z; r.w = x.w * w.w;
      o4[i] = r;
    }
    return;
  }

  const int xi = (bi >> 2) * 3 + (bi & 3);   // 0..4703
  const int mt  = xi % 196;
  const int snb = xi / 196;
  const int ori = snb >> 2;
  const int nb  = snb & 3;
  const int p0 = mt << 8;

  char* XB = reinterpret_cast<char*>(Xs);
  const char* WB = reinterpret_cast<const char*>(Ws);
  const float* xb = xh + (size_t)(nb * 32) * 9408 + ori * 1568;
  float* ob = out + 6422528 + (size_t)(nb * 32) * 9408 + ori * 1568;

  // ================= ISSUE PHASE: all global loads batched, no LDS writes =================
  // Thread t owns position P = p0 + t: 32 channel-major float2 loads, each
  // wave instruction covering 64 consecutive positions (512B contiguous).
  float2 R2[32];
  {
    const int P = p0 + t;
    const int bb = P / 784;
    const int hw = P - bb * 784;
    const float* s = xb + (size_t)bb * 1204224 + hw * 2;
#pragma unroll
    for (int c = 0; c < 32; ++c)
      R2[c] = *reinterpret_cast<const float2*>(s + (size_t)c * 9408);
  }
  uint4 Wr[4];                               // weight image chunks
  float Bv = 0.f;
  {
    const uint4* src = reinterpret_cast<const uint4*>(wg + nb * 8192);
#pragma unroll
    for (int it = 0; it < 4; ++it) Wr[it] = src[it * 256 + t];
  }
  if (t < 128) {
    const int layer = t >> 6, n = t & 63;
    const float* bsrc = layer ? b2 : b1;
    Bv = bsrc[((n >> 5) * 4 + nb) * 32 + (n & 31)];
  }
  __builtin_amdgcn_sched_barrier(0);         // loads stay ABOVE all LDS writes

  // ================= DRAIN PHASE: convert + LDS writes =================
  {
    uint4* dst = reinterpret_cast<uint4*>(Ws);
#pragma unroll
    for (int it = 0; it < 4; ++it) dst[it * 256 + t] = Wr[it];
  }
  if (t < 128) Bs[t] = Bv;
  // pack own row: row p = t; group g<4 = re of channels 8g.., g>=4 = im
  {
    const int prow = t;
    const int s0 = (prow >> 1) & 7;
    char* rowp = XB + prow * 128;
#pragma unroll
    for (int g = 0; g < 8; ++g) {
      const int cb = (g & 3) * 8;
      uint4 u;
      if (g < 4) {
        u.x = pack2(R2[cb + 0].x, R2[cb + 1].x);
        u.y = pack2(R2[cb + 2].x, R2[cb + 3].x);
        u.z = pack2(R2[cb + 4].x, R2[cb + 5].x);
        u.w = pack2(R2[cb + 6].x, R2[cb + 7].x);
      } else {
        u.x = pack2(R2[cb + 0].y, R2[cb + 1].y);
        u.y = pack2(R2[cb + 2].y, R2[cb + 3].y);
        u.z = pack2(R2[cb + 4].y, R2[cb + 5].y);
        u.w = pack2(R2[cb + 6].y, R2[cb + 7].y);
      }
      *reinterpret_cast<uint4*>(rowp + ((g ^ s0) * 16)) = u;
    }
  }
  __syncthreads();

  const int lane = t & 63;
  const int wv = t >> 6;
  const int lr = lane & 15;
  const int lg = lane >> 4;

  // ---- layer 1: D1[n][p] = W1t * X^T ----
  f32x4 acc[4][4];
#pragma unroll
  for (int mi = 0; mi < 4; ++mi)
#pragma unroll
    for (int ni = 0; ni < 4; ++ni)
      acc[mi][ni] = (f32x4){0.f, 0.f, 0.f, 0.f};

#pragma unroll
  for (int ks = 0; ks < 2; ++ks) {
    bf16x8 wf[4], xf[4];
#pragma unroll
    for (int mi = 0; mi < 4; ++mi) {
      const int n = mi * 16 + lr;
      wf[mi] = *reinterpret_cast<const bf16x8*>(WB + n * 128 + (((ks * 4 + lg) ^ ((n >> 1) & 7)) * 16));
    }
#pragma unroll
    for (int ni = 0; ni < 4; ++ni) {
      const int p = wv * 64 + ni * 16 + lr;
      xf[ni] = *reinterpret_cast<const bf16x8*>(XB + p * 128 + (((ks * 4 + lg) ^ ((p >> 1) & 7)) * 16));
    }
#pragma unroll
    for (int mi = 0; mi < 4; ++mi)
#pragma unroll
      for (int ni = 0; ni < 4; ++ni)
        acc[mi][ni] = __builtin_amdgcn_mfma_f32_16x16x32_bf16(wf[mi], xf[ni], acc[mi][ni], 0, 0, 0);
  }

  // ---- ep1: H = relu(D1 + b1) -> back into Xs (wave-private rows, no barrier) ----
#pragma unroll
  for (int mi = 0; mi < 4; ++mi) {
    const f32x4 bv = *reinterpret_cast<const f32x4*>(&Bs[mi * 16 + lg * 4]);
    const int gH = mi * 2 + (lg >> 1);
    const int offH = (lg & 1) * 8;
#pragma unroll
    for (int ni = 0; ni < 4; ++ni) {
      const int p = wv * 64 + ni * 16 + lr;
      const float h0 = fmaxf(acc[mi][ni][0] + bv[0], 0.f);
      const float h1 = fmaxf(acc[mi][ni][1] + bv[1], 0.f);
      const float h2 = fmaxf(acc[mi][ni][2] + bv[2], 0.f);
      const float h3 = fmaxf(acc[mi][ni][3] + bv[3], 0.f);
      uint2 u; u.x = pack2(h0, h1); u.y = pack2(h2, h3);
      *reinterpret_cast<uint2*>(XB + p * 128 + ((gH ^ ((p >> 1) & 7)) * 16) + offH) = u;
    }
  }

  // ---- layer 2: D2[n][p] = W2t * H^T (wave-private rows) ----
  f32x4 acc2[4][4];
#pragma unroll
  for (int mi = 0; mi < 4; ++mi)
#pragma unroll
    for (int ni = 0; ni < 4; ++ni)
      acc2[mi][ni] = (f32x4){0.f, 0.f, 0.f, 0.f};

#pragma unroll
  for (int ks = 0; ks < 2; ++ks) {
    bf16x8 wf[4], hf[4];
#pragma unroll
    for (int mi = 0; mi < 4; ++mi) {
      const int n = mi * 16 + lr;
      wf[mi] = *reinterpret_cast<const bf16x8*>(WB + 8192 + n * 128 + (((ks * 4 + lg) ^ ((n >> 1) & 7)) * 16));
    }
#pragma unroll
    for (int ni = 0; ni < 4; ++ni) {
      const int p = wv * 64 + ni * 16 + lr;
      hf[ni] = *reinterpret_cast<const bf16x8*>(XB + p * 128 + (((ks * 4 + lg) ^ ((p >> 1) & 7)) * 16));
    }
#pragma unroll
    for (int mi = 0; mi < 4; ++mi)
#pragma unroll
      for (int ni = 0; ni < 4; ++ni)
        acc2[mi][ni] = __builtin_amdgcn_mfma_f32_16x16x32_bf16(wf[mi], hf[ni], acc2[mi][ni], 0, 0, 0);
  }

  // ---- ep2: out = D2 + b2, interleaved (re,im) float2 stores ----
#pragma unroll
  for (int ni = 0; ni < 4; ++ni) {
    const int p = wv * 64 + ni * 16 + lr;
    const int P = p0 + p;
    const int bb = P / 784;
    const int hw = P - bb * 784;
    float* obase = ob + (size_t)bb * 1204224 + hw * 2;
#pragma unroll
    for (int mi = 0; mi < 2; ++mi) {
      const f32x4 bre = *reinterpret_cast<const f32x4*>(&Bs[64 + mi * 16 + lg * 4]);
      const f32x4 bim = *reinterpret_cast<const f32x4*>(&Bs[64 + (mi + 2) * 16 + lg * 4]);
#pragma unroll
      for (int j = 0; j < 4; ++j) {
        const int c = mi * 16 + lg * 4 + j;
        float2 v;
        v.x = acc2[mi][ni][j] + bre[j];
        v.y = acc2[mi + 2][ni][j] + bim[j];
        *reinterpret_cast<float2*>(obase + (size_t)c * 9408) = v;
      }
    }
  }
}

extern "C" void kernel_launch(void* const* d_in, const int* in_sizes, int n_in,
                              void* d_out, int out_size, void* d_ws, size_t ws_size,
                              hipStream_t stream) {
  (void)in_sizes; (void)n_in; (void)out_size; (void)ws_size;
  const float* xl  = (const float*)d_in[0];
  const float* xh  = (const float*)d_in[1];
  const float* wll = (const float*)d_in[2];
  const float* w1  = (const float*)d_in[3];
  const float* w2  = (const float*)d_in[4];
  const float* b1  = (const float*)d_in[5];
  const float* b2  = (const float*)d_in[6];
  float* out = (float*)d_out;
  unsigned short* wg = (unsigned short*)d_ws;   // 65536 bytes used

  prep_weights<<<128, 256, 0, stream>>>(w1, w2, wg);
  fused_kernel<<<6272, 256, 0, stream>>>(xh, wg, b1, b2, xl, wll, out);
}

// Round 8
// 148.563 us; speedup vs baseline: 1.0819x; 1.0106x over previous
//
#include <hip/hip_runtime.h>

typedef __bf16 bf16x8 __attribute__((ext_vector_type(8)));
typedef float  f32x4  __attribute__((ext_vector_type(4)));

// Sizes: B=64, C=128, ORI=6, HW=784, NB=4, BS=32
// xh strides (floats): b:1204224, c:9408, ori:1568, hw:2, ri:1

static __device__ __forceinline__ unsigned short bf16bits(float f) {
  __bf16 h = (__bf16)f; return __builtin_bit_cast(unsigned short, h);
}
static __device__ __forceinline__ unsigned int pack2(float a, float b) {
  return (unsigned int)bf16bits(a) | ((unsigned int)bf16bits(b) << 16);
}

// ---------------- weight prep: combined real matrix, transposed [n][k], bf16,
// written as the PRE-SWIZZLED LDS image so the main kernel does a linear copy.
__global__ void prep_weights(const float* __restrict__ w1, const float* __restrict__ w2,
                             unsigned short* __restrict__ wg) {
  const int e = blockIdx.x * 256 + threadIdx.x;      // 0..32767
  const int nb    = e >> 13;
  const int layer = (e >> 12) & 1;
  const int n = (e >> 6) & 63;
  const int k = e & 63;
  const float* w = layer ? w2 : w1;
  const int kk = k & 31, nn = n & 31;
  float v;
  if (n < 32) {
    v = (k < 32) ?  w[((0 * 4 + nb) * 32 + kk) * 32 + nn]
                 : -w[((1 * 4 + nb) * 32 + kk) * 32 + nn];
  } else {
    v = (k < 32) ?  w[((1 * 4 + nb) * 32 + kk) * 32 + nn]
                 :  w[((0 * 4 + nb) * 32 + kk) * 32 + nn];
  }
  const int pos = nb * 8192 + layer * 4096 + n * 64 + (((k >> 3) ^ ((n >> 1) & 7)) * 8) + (k & 7);
  wg[pos] = bf16bits(v);
}

// ---------------- fused main kernel ----------------
// grid = 6272: (bi&3)==3 -> lowpass block (1568); else xh block (4704)
// xh loads: thread t owns positions 2*(t&127),+1 and channels (t>>7)*16..+15;
// each wave load instruction = 64 lanes x 16B = 1024B single contiguous segment.
__global__ __launch_bounds__(256, 3)
void fused_kernel(const float* __restrict__ xh, const unsigned short* __restrict__ wg,
                  const float* __restrict__ b1, const float* __restrict__ b2,
                  const float* __restrict__ xl, const float* __restrict__ wll,
                  float* __restrict__ out) {
  __shared__ __align__(16) unsigned short Xs[256 * 64];   // X tile -> H tile (bf16), 32KB
  __shared__ __align__(16) unsigned short Ws[2 * 64 * 64];// 16KB pre-swizzled weight image
  __shared__ __align__(16) float Bs[128];

  const int t = threadIdx.x;
  const int bi = blockIdx.x;

  if ((bi & 3) == 3) {                    // ---- lowpass path: xl_out = xl * w_ll ----
    const int llb = bi >> 2;              // 0..1567, 1024 float4 each
    const float4* xi4 = reinterpret_cast<const float4*>(xl);
    const float4* w4  = reinterpret_cast<const float4*>(wll);
    float4* o4 = reinterpret_cast<float4*>(out);
#pragma unroll
    for (int j = 0; j < 4; ++j) {
      const int i = llb * 1024 + j * 256 + t;
      const float4 x = xi4[i];
      const float4 w = w4[i % 25088];
      float4 r; r.x = x.x * w.x; r.y = x.y * w.y; r.z = x.z * w.z; r.w = x.w * w.w;
      o4[i] = r;
    }
    return;
  }

  const int xi = (bi >> 2) * 3 + (bi & 3);   // 0..4703
  const int mt  = xi % 196;
  const int snb = xi / 196;
  const int ori = snb >> 2;
  const int nb  = snb & 3;
  const int p0 = mt << 8;

  char* XB = reinterpret_cast<char*>(Xs);
  const char* WB = reinterpret_cast<const char*>(Ws);
  const float* xb = xh + (size_t)(nb * 32) * 9408 + ori * 1568;
  float* ob = out + 6422528 + (size_t)(nb * 32) * 9408 + ori * 1568;

  // ================= ISSUE PHASE: all global loads batched, no LDS writes =================
  // thread t: positions p=2*(t&127), p+1; channels c16*16 .. +15
  f32x4 R[16];
  const int pp  = t & 127;
  const int c16 = t >> 7;
  {
    const int P = p0 + 2 * pp;
    const int bb = P / 784;
    const int hw = P - bb * 784;                 // even; P,P+1 share bb
    const float* s = xb + (size_t)bb * 1204224 + (size_t)(c16 * 16) * 9408 + hw * 2;
#pragma unroll
    for (int j = 0; j < 16; ++j)
      R[j] = *reinterpret_cast<const f32x4*>(s + (size_t)j * 9408);  // re(p),im(p),re(p+1),im(p+1)
  }
  uint4 Wr[4];                               // weight image chunks
  float Bv = 0.f;
  {
    const uint4* src = reinterpret_cast<const uint4*>(wg + nb * 8192);
#pragma unroll
    for (int it = 0; it < 4; ++it) Wr[it] = src[it * 256 + t];
  }
  if (t < 128) {
    const int layer = t >> 6, n = t & 63;
    const float* bsrc = layer ? b2 : b1;
    Bv = bsrc[((n >> 5) * 4 + nb) * 32 + (n & 31)];
  }
  __builtin_amdgcn_sched_barrier(0);         // loads stay ABOVE all LDS writes

  // ================= DRAIN PHASE: convert + LDS writes =================
  {
    uint4* dst = reinterpret_cast<uint4*>(Ws);
#pragma unroll
    for (int it = 0; it < 4; ++it) dst[it * 256 + t] = Wr[it];
  }
  if (t < 128) Bs[t] = Bv;
  // pack rows p=2*pp and p+1: re groups g=2*c16+{0,1}, im groups +4; slot = g ^ s0
  {
    const int p = 2 * pp;
    const int s0 = pp & 7;                     // (p>>1)&7, same for p and p+1
    char* row0 = XB + p * 128;
    char* row1 = XB + (p + 1) * 128;
    uint4 u;
    // row p, re, channels c16*16..+7  -> group 2*c16
    u.x = pack2(R[0].x, R[1].x);  u.y = pack2(R[2].x, R[3].x);
    u.z = pack2(R[4].x, R[5].x);  u.w = pack2(R[6].x, R[7].x);
    *reinterpret_cast<uint4*>(row0 + (((2 * c16 + 0) ^ s0) * 16)) = u;
    // row p, re, channels +8..15 -> group 2*c16+1
    u.x = pack2(R[8].x, R[9].x);  u.y = pack2(R[10].x, R[11].x);
    u.z = pack2(R[12].x, R[13].x); u.w = pack2(R[14].x, R[15].x);
    *reinterpret_cast<uint4*>(row0 + (((2 * c16 + 1) ^ s0) * 16)) = u;
    // row p, im -> groups +4
    u.x = pack2(R[0].y, R[1].y);  u.y = pack2(R[2].y, R[3].y);
    u.z = pack2(R[4].y, R[5].y);  u.w = pack2(R[6].y, R[7].y);
    *reinterpret_cast<uint4*>(row0 + (((2 * c16 + 4) ^ s0) * 16)) = u;
    u.x = pack2(R[8].y, R[9].y);  u.y = pack2(R[10].y, R[11].y);
    u.z = pack2(R[12].y, R[13].y); u.w = pack2(R[14].y, R[15].y);
    *reinterpret_cast<uint4*>(row0 + (((2 * c16 + 5) ^ s0) * 16)) = u;
    // row p+1, re
    u.x = pack2(R[0].z, R[1].z);  u.y = pack2(R[2].z, R[3].z);
    u.z = pack2(R[4].z, R[5].z);  u.w = pack2(R[6].z, R[7].z);
    *reinterpret_cast<uint4*>(row1 + (((2 * c16 + 0) ^ s0) * 16)) = u;
    u.x = pack2(R[8].z, R[9].z);  u.y = pack2(R[10].z, R[11].z);
    u.z = pack2(R[12].z, R[13].z); u.w = pack2(R[14].z, R[15].z);
    *reinterpret_cast<uint4*>(row1 + (((2 * c16 + 1) ^ s0) * 16)) = u;
    // row p+1, im
    u.x = pack2(R[0].w, R[1].w);  u.y = pack2(R[2].w, R[3].w);
    u.z = pack2(R[4].w, R[5].w);  u.w = pack2(R[6].w, R[7].w);
    *reinterpret_cast<uint4*>(row1 + (((2 * c16 + 4) ^ s0) * 16)) = u;
    u.x = pack2(R[8].w, R[9].w);  u.y = pack2(R[10].w, R[11].w);
    u.z = pack2(R[12].w, R[13].w); u.w = pack2(R[14].w, R[15].w);
    *reinterpret_cast<uint4*>(row1 + (((2 * c16 + 5) ^ s0) * 16)) = u;
  }
  __syncthreads();

  const int lane = t & 63;
  const int wv = t >> 6;
  const int lr = lane & 15;
  const int lg = lane >> 4;

  // ---- layer 1: D1[n][p] = W1t * X^T ----
  f32x4 acc[4][4];
#pragma unroll
  for (int mi = 0; mi < 4; ++mi)
#pragma unroll
    for (int ni = 0; ni < 4; ++ni)
      acc[mi][ni] = (f32x4){0.f, 0.f, 0.f, 0.f};

#pragma unroll
  for (int ks = 0; ks < 2; ++ks) {
    bf16x8 wf[4], xf[4];
#pragma unroll
    for (int mi = 0; mi < 4; ++mi) {
      const int n = mi * 16 + lr;
      wf[mi] = *reinterpret_cast<const bf16x8*>(WB + n * 128 + (((ks * 4 + lg) ^ ((n >> 1) & 7)) * 16));
    }
#pragma unroll
    for (int ni = 0; ni < 4; ++ni) {
      const int p = wv * 64 + ni * 16 + lr;
      xf[ni] = *reinterpret_cast<const bf16x8*>(XB + p * 128 + (((ks * 4 + lg) ^ ((p >> 1) & 7)) * 16));
    }
#pragma unroll
    for (int mi = 0; mi < 4; ++mi)
#pragma unroll
      for (int ni = 0; ni < 4; ++ni)
        acc[mi][ni] = __builtin_amdgcn_mfma_f32_16x16x32_bf16(wf[mi], xf[ni], acc[mi][ni], 0, 0, 0);
  }

  // ---- ep1: H = relu(D1 + b1) -> back into Xs (wave-private rows, no barrier) ----
#pragma unroll
  for (int mi = 0; mi < 4; ++mi) {
    const f32x4 bv = *reinterpret_cast<const f32x4*>(&Bs[mi * 16 + lg * 4]);
    const int gH = mi * 2 + (lg >> 1);
    const int offH = (lg & 1) * 8;
#pragma unroll
    for (int ni = 0; ni < 4; ++ni) {
      const int p = wv * 64 + ni * 16 + lr;
      const float h0 = fmaxf(acc[mi][ni][0] + bv[0], 0.f);
      const float h1 = fmaxf(acc[mi][ni][1] + bv[1], 0.f);
      const float h2 = fmaxf(acc[mi][ni][2] + bv[2], 0.f);
      const float h3 = fmaxf(acc[mi][ni][3] + bv[3], 0.f);
      uint2 u; u.x = pack2(h0, h1); u.y = pack2(h2, h3);
      *reinterpret_cast<uint2*>(XB + p * 128 + ((gH ^ ((p >> 1) & 7)) * 16) + offH) = u;
    }
  }

  // ---- layer 2: D2[n][p] = W2t * H^T (wave-private rows) ----
  f32x4 acc2[4][4];
#pragma unroll
  for (int mi = 0; mi < 4; ++mi)
#pragma unroll
    for (int ni = 0; ni < 4; ++ni)
      acc2[mi][ni] = (f32x4){0.f, 0.f, 0.f, 0.f};

#pragma unroll
  for (int ks = 0; ks < 2; ++ks) {
    bf16x8 wf[4], hf[4];
#pragma unroll
    for (int mi = 0; mi < 4; ++mi) {
      const int n = mi * 16 + lr;
      wf[mi] = *reinterpret_cast<const bf16x8*>(WB + 8192 + n * 128 + (((ks * 4 + lg) ^ ((n >> 1) & 7)) * 16));
    }
#pragma unroll
    for (int ni = 0; ni < 4; ++ni) {
      const int p = wv * 64 + ni * 16 + lr;
      hf[ni] = *reinterpret_cast<const bf16x8*>(XB + p * 128 + (((ks * 4 + lg) ^ ((p >> 1) & 7)) * 16));
    }
#pragma unroll
    for (int mi = 0; mi < 4; ++mi)
#pragma unroll
      for (int ni = 0; ni < 4; ++ni)
        acc2[mi][ni] = __builtin_amdgcn_mfma_f32_16x16x32_bf16(wf[mi], hf[ni], acc2[mi][ni], 0, 0, 0);
  }

  // ---- ep2: out = D2 + b2, interleaved (re,im) float2 stores ----
#pragma unroll
  for (int ni = 0; ni < 4; ++ni) {
    const int p = wv * 64 + ni * 16 + lr;
    const int P = p0 + p;
    const int bb = P / 784;
    const int hw = P - bb * 784;
    float* obase = ob + (size_t)bb * 1204224 + hw * 2;
#pragma unroll
    for (int mi = 0; mi < 2; ++mi) {
      const f32x4 bre = *reinterpret_cast<const f32x4*>(&Bs[64 + mi * 16 + lg * 4]);
      const f32x4 bim = *reinterpret_cast<const f32x4*>(&Bs[64 + (mi + 2) * 16 + lg * 4]);
#pragma unroll
      for (int j = 0; j < 4; ++j) {
        const int c = mi * 16 + lg * 4 + j;
        float2 v;
        v.x = acc2[mi][ni][j] + bre[j];
        v.y = acc2[mi + 2][ni][j] + bim[j];
        *reinterpret_cast<float2*>(obase + (size_t)c * 9408) = v;
      }
    }
  }
}

extern "C" void kernel_launch(void* const* d_in, const int* in_sizes, int n_in,
                              void* d_out, int out_size, void* d_ws, size_t ws_size,
                              hipStream_t stream) {
  (void)in_sizes; (void)n_in; (void)out_size; (void)ws_size;
  const float* xl  = (const float*)d_in[0];
  const float* xh  = (const float*)d_in[1];
  const float* wll = (const float*)d_in[2];
  const float* w1  = (const float*)d_in[3];
  const float* w2  = (const float*)d_in[4];
  const float* b1  = (const float*)d_in[5];
  const float* b2  = (const float*)d_in[6];
  float* out = (float*)d_out;
  unsigned short* wg = (unsigned short*)d_ws;   // 65536 bytes used

  prep_weights<<<128, 256, 0, stream>>>(w1, w2, wg);
  fused_kernel<<<6272, 256, 0, stream>>>(xh, wg, b1, b2, xl, wll, out);
}

// Round 9
// 148.007 us; speedup vs baseline: 1.0859x; 1.0038x over previous
//
#include <hip/hip_runtime.h>

typedef __bf16 bf16x8 __attribute__((ext_vector_type(8)));
typedef float  f32x4  __attribute__((ext_vector_type(4)));

// Sizes: B=64, C=128, ORI=6, HW=784, NB=4, BS=32
// xh strides (floats): b:1204224, c:9408, ori:1568, hw:2, ri:1

static __device__ __forceinline__ unsigned short bf16bits(float f) {
  __bf16 h = (__bf16)f; return __builtin_bit_cast(unsigned short, h);
}
static __device__ __forceinline__ unsigned int pack2(float a, float b) {
  return (unsigned int)bf16bits(a) | ((unsigned int)bf16bits(b) << 16);
}

// ---------------- weight prep: combined real matrix, transposed [n][k], bf16,
// written as the PRE-SWIZZLED LDS image so the main kernel does a linear copy.
__global__ void prep_weights(const float* __restrict__ w1, const float* __restrict__ w2,
                             unsigned short* __restrict__ wg) {
  const int e = blockIdx.x * 256 + threadIdx.x;      // 0..32767
  const int nb    = e >> 13;
  const int layer = (e >> 12) & 1;
  const int n = (e >> 6) & 63;
  const int k = e & 63;
  const float* w = layer ? w2 : w1;
  const int kk = k & 31, nn = n & 31;
  float v;
  if (n < 32) {
    v = (k < 32) ?  w[((0 * 4 + nb) * 32 + kk) * 32 + nn]
                 : -w[((1 * 4 + nb) * 32 + kk) * 32 + nn];
  } else {
    v = (k < 32) ?  w[((1 * 4 + nb) * 32 + kk) * 32 + nn]
                 :  w[((0 * 4 + nb) * 32 + kk) * 32 + nn];
  }
  const int pos = nb * 8192 + layer * 4096 + n * 64 + (((k >> 3) ^ ((n >> 1) & 7)) * 8) + (k & 7);
  wg[pos] = bf16bits(v);
}

// ---------------- fused main kernel ----------------
// grid = 6272: (bi&3)==3 -> lowpass block (1568); else xh block (4704)
// xh loads: 1KB single-segment per wave instruction (R8 shape).
// xh stores: NEW -- transpose through freed Xs, 1KB single-segment float4 stores.
__global__ __launch_bounds__(256, 3)
void fused_kernel(const float* __restrict__ xh, const unsigned short* __restrict__ wg,
                  const float* __restrict__ b1, const float* __restrict__ b2,
                  const float* __restrict__ xl, const float* __restrict__ wll,
                  float* __restrict__ out) {
  __shared__ __align__(16) unsigned short Xs[256 * 64];   // X tile -> H tile -> out staging, 32KB
  __shared__ __align__(16) unsigned short Ws[2 * 64 * 64];// 16KB pre-swizzled weight image
  __shared__ __align__(16) float Bs[128];

  const int t = threadIdx.x;
  const int bi = blockIdx.x;

  if ((bi & 3) == 3) {                    // ---- lowpass path: xl_out = xl * w_ll ----
    const int llb = bi >> 2;              // 0..1567, 1024 float4 each
    const float4* xi4 = reinterpret_cast<const float4*>(xl);
    const float4* w4  = reinterpret_cast<const float4*>(wll);
    float4* o4 = reinterpret_cast<float4*>(out);
#pragma unroll
    for (int j = 0; j < 4; ++j) {
      const int i = llb * 1024 + j * 256 + t;
      const float4 x = xi4[i];
      const float4 w = w4[i % 25088];
      float4 r; r.x = x.x * w.x; r.y = x.y * w.y; r.z = x.z * w.z; r.w = x.w * w.w;
      o4[i] = r;
    }
    return;
  }

  const int xi = (bi >> 2) * 3 + (bi & 3);   // 0..4703
  const int mt  = xi % 196;
  const int snb = xi / 196;
  const int ori = snb >> 2;
  const int nb  = snb & 3;
  const int p0 = mt << 8;

  char* XB = reinterpret_cast<char*>(Xs);
  const char* WB = reinterpret_cast<const char*>(Ws);
  const float* xb = xh + (size_t)(nb * 32) * 9408 + ori * 1568;
  float* ob = out + 6422528 + (size_t)(nb * 32) * 9408 + ori * 1568;

  // ================= ISSUE PHASE: all global loads batched, no LDS writes =================
  // thread t: positions p=2*(t&127), p+1; channels (t>>7)*16 .. +15
  f32x4 R[16];
  const int pp  = t & 127;
  const int c16 = t >> 7;
  {
    const int P = p0 + 2 * pp;
    const int bb = P / 784;
    const int hw = P - bb * 784;                 // even; P,P+1 share bb
    const float* s = xb + (size_t)bb * 1204224 + (size_t)(c16 * 16) * 9408 + hw * 2;
#pragma unroll
    for (int j = 0; j < 16; ++j)
      R[j] = *reinterpret_cast<const f32x4*>(s + (size_t)j * 9408);  // re(p),im(p),re(p+1),im(p+1)
  }
  uint4 Wr[4];                               // weight image chunks
  float Bv = 0.f;
  {
    const uint4* src = reinterpret_cast<const uint4*>(wg + nb * 8192);
#pragma unroll
    for (int it = 0; it < 4; ++it) Wr[it] = src[it * 256 + t];
  }
  if (t < 128) {
    const int layer = t >> 6, n = t & 63;
    const float* bsrc = layer ? b2 : b1;
    Bv = bsrc[((n >> 5) * 4 + nb) * 32 + (n & 31)];
  }
  __builtin_amdgcn_sched_barrier(0);         // loads stay ABOVE all LDS writes

  // ================= DRAIN PHASE: convert + LDS writes =================
  {
    uint4* dst = reinterpret_cast<uint4*>(Ws);
#pragma unroll
    for (int it = 0; it < 4; ++it) dst[it * 256 + t] = Wr[it];
  }
  if (t < 128) Bs[t] = Bv;
  // pack rows p=2*pp and p+1: re groups g=2*c16+{0,1}, im groups +4; slot = g ^ s0
  {
    const int p = 2 * pp;
    const int s0 = pp & 7;                     // (p>>1)&7, same for p and p+1
    char* row0 = XB + p * 128;
    char* row1 = XB + (p + 1) * 128;
    uint4 u;
    u.x = pack2(R[0].x, R[1].x);  u.y = pack2(R[2].x, R[3].x);
    u.z = pack2(R[4].x, R[5].x);  u.w = pack2(R[6].x, R[7].x);
    *reinterpret_cast<uint4*>(row0 + (((2 * c16 + 0) ^ s0) * 16)) = u;
    u.x = pack2(R[8].x, R[9].x);  u.y = pack2(R[10].x, R[11].x);
    u.z = pack2(R[12].x, R[13].x); u.w = pack2(R[14].x, R[15].x);
    *reinterpret_cast<uint4*>(row0 + (((2 * c16 + 1) ^ s0) * 16)) = u;
    u.x = pack2(R[0].y, R[1].y);  u.y = pack2(R[2].y, R[3].y);
    u.z = pack2(R[4].y, R[5].y);  u.w = pack2(R[6].y, R[7].y);
    *reinterpret_cast<uint4*>(row0 + (((2 * c16 + 4) ^ s0) * 16)) = u;
    u.x = pack2(R[8].y, R[9].y);  u.y = pack2(R[10].y, R[11].y);
    u.z = pack2(R[12].y, R[13].y); u.w = pack2(R[14].y, R[15].y);
    *reinterpret_cast<uint4*>(row0 + (((2 * c16 + 5) ^ s0) * 16)) = u;
    u.x = pack2(R[0].z, R[1].z);  u.y = pack2(R[2].z, R[3].z);
    u.z = pack2(R[4].z, R[5].z);  u.w = pack2(R[6].z, R[7].z);
    *reinterpret_cast<uint4*>(row1 + (((2 * c16 + 0) ^ s0) * 16)) = u;
    u.x = pack2(R[8].z, R[9].z);  u.y = pack2(R[10].z, R[11].z);
    u.z = pack2(R[12].z, R[13].z); u.w = pack2(R[14].z, R[15].z);
    *reinterpret_cast<uint4*>(row1 + (((2 * c16 + 1) ^ s0) * 16)) = u;
    u.x = pack2(R[0].w, R[1].w);  u.y = pack2(R[2].w, R[3].w);
    u.z = pack2(R[4].w, R[5].w);  u.w = pack2(R[6].w, R[7].w);
    *reinterpret_cast<uint4*>(row1 + (((2 * c16 + 4) ^ s0) * 16)) = u;
    u.x = pack2(R[8].w, R[9].w);  u.y = pack2(R[10].w, R[11].w);
    u.z = pack2(R[12].w, R[13].w); u.w = pack2(R[14].w, R[15].w);
    *reinterpret_cast<uint4*>(row1 + (((2 * c16 + 5) ^ s0) * 16)) = u;
  }
  __syncthreads();

  const int lane = t & 63;
  const int wv = t >> 6;
  const int lr = lane & 15;
  const int lg = lane >> 4;

  // ---- layer 1: D1[n][p] = W1t * X^T ----
  f32x4 acc[4][4];
#pragma unroll
  for (int mi = 0; mi < 4; ++mi)
#pragma unroll
    for (int ni = 0; ni < 4; ++ni)
      acc[mi][ni] = (f32x4){0.f, 0.f, 0.f, 0.f};

#pragma unroll
  for (int ks = 0; ks < 2; ++ks) {
    bf16x8 wf[4], xf[4];
#pragma unroll
    for (int mi = 0; mi < 4; ++mi) {
      const int n = mi * 16 + lr;
      wf[mi] = *reinterpret_cast<const bf16x8*>(WB + n * 128 + (((ks * 4 + lg) ^ ((n >> 1) & 7)) * 16));
    }
#pragma unroll
    for (int ni = 0; ni < 4; ++ni) {
      const int p = wv * 64 + ni * 16 + lr;
      xf[ni] = *reinterpret_cast<const bf16x8*>(XB + p * 128 + (((ks * 4 + lg) ^ ((p >> 1) & 7)) * 16));
    }
#pragma unroll
    for (int mi = 0; mi < 4; ++mi)
#pragma unroll
      for (int ni = 0; ni < 4; ++ni)
        acc[mi][ni] = __builtin_amdgcn_mfma_f32_16x16x32_bf16(wf[mi], xf[ni], acc[mi][ni], 0, 0, 0);
  }

  // ---- ep1: H = relu(D1 + b1) -> back into Xs (wave-private rows, no barrier) ----
#pragma unroll
  for (int mi = 0; mi < 4; ++mi) {
    const f32x4 bv = *reinterpret_cast<const f32x4*>(&Bs[mi * 16 + lg * 4]);
    const int gH = mi * 2 + (lg >> 1);
    const int offH = (lg & 1) * 8;
#pragma unroll
    for (int ni = 0; ni < 4; ++ni) {
      const int p = wv * 64 + ni * 16 + lr;
      const float h0 = fmaxf(acc[mi][ni][0] + bv[0], 0.f);
      const float h1 = fmaxf(acc[mi][ni][1] + bv[1], 0.f);
      const float h2 = fmaxf(acc[mi][ni][2] + bv[2], 0.f);
      const float h3 = fmaxf(acc[mi][ni][3] + bv[3], 0.f);
      uint2 u; u.x = pack2(h0, h1); u.y = pack2(h2, h3);
      *reinterpret_cast<uint2*>(XB + p * 128 + ((gH ^ ((p >> 1) & 7)) * 16) + offH) = u;
    }
  }

  // ---- layer 2: D2[n][p] = W2t * H^T (wave-private rows) ----
  f32x4 acc2[4][4];
#pragma unroll
  for (int mi = 0; mi < 4; ++mi)
#pragma unroll
    for (int ni = 0; ni < 4; ++ni)
      acc2[mi][ni] = (f32x4){0.f, 0.f, 0.f, 0.f};

#pragma unroll
  for (int ks = 0; ks < 2; ++ks) {
    bf16x8 wf[4], hf[4];
#pragma unroll
    for (int mi = 0; mi < 4; ++mi) {
      const int n = mi * 16 + lr;
      wf[mi] = *reinterpret_cast<const bf16x8*>(WB + 8192 + n * 128 + (((ks * 4 + lg) ^ ((n >> 1) & 7)) * 16));
    }
#pragma unroll
    for (int ni = 0; ni < 4; ++ni) {
      const int p = wv * 64 + ni * 16 + lr;
      hf[ni] = *reinterpret_cast<const bf16x8*>(XB + p * 128 + (((ks * 4 + lg) ^ ((p >> 1) & 7)) * 16));
    }
#pragma unroll
    for (int mi = 0; mi < 4; ++mi)
#pragma unroll
      for (int ni = 0; ni < 4; ++ni)
        acc2[mi][ni] = __builtin_amdgcn_mfma_f32_16x16x32_bf16(wf[mi], hf[ni], acc2[mi][ni], 0, 0, 0);
  }

  // ---- ep2 NEW: transpose-store through freed Xs (f32 staging, 2 channel-half passes) ----
  // staging: row pp in [0,128), 16 slots of 16B; slot' = chl ^ (pp&15);
  // slot holds {re(2pp),im(2pp),re(2pp+1),im(2pp+1)} of channel chl.
  // Wave wv's rows [wv*32, wv*32+32) occupy bytes [wv*8192,+8192) = its own H bytes.
#pragma unroll
  for (int pass = 0; pass < 2; ++pass) {
#pragma unroll
    for (int ni = 0; ni < 4; ++ni) {
#pragma unroll
      for (int j = 0; j < 4; ++j) {
        const int chl = lg * 4 + j;            // channel-in-pass 0..15
        const int c = pass * 16 + chl;
        const int p = wv * 64 + ni * 16 + lr;
        const int prow = p >> 1;
        float2 v;
        v.x = acc2[pass][ni][j]     + Bs[64 + c];
        v.y = acc2[pass + 2][ni][j] + Bs[96 + c];
        *reinterpret_cast<float2*>(XB + prow * 256 + ((chl ^ (prow & 15)) * 16) + (p & 1) * 8) = v;
      }
    }
    __syncthreads();                           // staging visible to all waves
#pragma unroll
    for (int i = 0; i < 8; ++i) {
      const int chl = wv * 4 + (i >> 1);
      const int h = i & 1;
      const int idx = h * 64 + lane;           // row pp, 0..127
      const float4 v = *reinterpret_cast<const float4*>(XB + idx * 256 + ((chl ^ (idx & 15)) * 16));
      const int c = pass * 16 + chl;
      const int P = p0 + 2 * idx;
      const int bb = P / 784;
      const int hw = P - bb * 784;
      *reinterpret_cast<float4*>(ob + (size_t)bb * 1204224 + (size_t)c * 9408 + hw * 2) = v;
    }
    if (pass == 0) __syncthreads();            // all store-reads done before restaging
  }
}

extern "C" void kernel_launch(void* const* d_in, const int* in_sizes, int n_in,
                              void* d_out, int out_size, void* d_ws, size_t ws_size,
                              hipStream_t stream) {
  (void)in_sizes; (void)n_in; (void)out_size; (void)ws_size;
  const float* xl  = (const float*)d_in[0];
  const float* xh  = (const float*)d_in[1];
  const float* wll = (const float*)d_in[2];
  const float* w1  = (const float*)d_in[3];
  const float* w2  = (const float*)d_in[4];
  const float* b1  = (const float*)d_in[5];
  const float* b2  = (const float*)d_in[6];
  float* out = (float*)d_out;
  unsigned short* wg = (unsigned short*)d_ws;   // 65536 bytes used

  prep_weights<<<128, 256, 0, stream>>>(w1, w2, wg);
  fused_kernel<<<6272, 256, 0, stream>>>(xh, wg, b1, b2, xl, wll, out);
}

// Round 10
// 143.544 us; speedup vs baseline: 1.1197x; 1.0311x over previous
//
#include <hip/hip_runtime.h>

typedef __bf16 bf16x8 __attribute__((ext_vector_type(8)));
typedef float  f32x4  __attribute__((ext_vector_type(4)));

// Sizes: B=64, C=128, ORI=6, HW=784, NB=4, BS=32
// xh strides (floats): b:1204224, c:9408, ori:1568, hw:2, ri:1

static __device__ __forceinline__ unsigned short bf16bits(float f) {
  __bf16 h = (__bf16)f; return __builtin_bit_cast(unsigned short, h);
}
static __device__ __forceinline__ unsigned int pack2(float a, float b) {
  return (unsigned int)bf16bits(a) | ((unsigned int)bf16bits(b) << 16);
}

// ---------------- weight prep: combined real matrix, transposed [n][k], bf16,
// written as the PRE-SWIZZLED LDS image so the main kernel does a linear copy.
__global__ void prep_weights(const float* __restrict__ w1, const float* __restrict__ w2,
                             unsigned short* __restrict__ wg) {
  const int e = blockIdx.x * 256 + threadIdx.x;      // 0..32767
  const int nb    = e >> 13;
  const int layer = (e >> 12) & 1;
  const int n = (e >> 6) & 63;
  const int k = e & 63;
  const float* w = layer ? w2 : w1;
  const int kk = k & 31, nn = n & 31;
  float v;
  if (n < 32) {
    v = (k < 32) ?  w[((0 * 4 + nb) * 32 + kk) * 32 + nn]
                 : -w[((1 * 4 + nb) * 32 + kk) * 32 + nn];
  } else {
    v = (k < 32) ?  w[((1 * 4 + nb) * 32 + kk) * 32 + nn]
                 :  w[((0 * 4 + nb) * 32 + kk) * 32 + nn];
  }
  const int pos = nb * 8192 + layer * 4096 + n * 64 + (((k >> 3) ^ ((n >> 1) & 7)) * 8) + (k & 7);
  wg[pos] = bf16bits(v);
}

// ---------------- fused main kernel, HALF tiles for 4 blocks/CU ----------------
// grid = 10976: bi < 9408 -> xh block (ori, nb, 128-position tile); else lowpass.
// 24 snb * 392 tiles; tile = 128 positions. LDS = 16KB Xs + 16KB Ws + 0.5KB Bs.
__global__ __launch_bounds__(256, 4)
void fused_kernel(const float* __restrict__ xh, const unsigned short* __restrict__ wg,
                  const float* __restrict__ b1, const float* __restrict__ b2,
                  const float* __restrict__ xl, const float* __restrict__ wll,
                  float* __restrict__ out) {
  __shared__ __align__(16) unsigned short Xs[128 * 64];   // X tile -> H tile (bf16), 16KB
  __shared__ __align__(16) unsigned short Ws[2 * 64 * 64];// 16KB pre-swizzled weight image
  __shared__ __align__(16) float Bs[128];

  const int t = threadIdx.x;
  const int bi = blockIdx.x;

  if (bi >= 9408) {                       // ---- lowpass path: xl_out = xl * w_ll ----
    const int llb = bi - 9408;            // 0..1567, 1024 float4 each
    const float4* xi4 = reinterpret_cast<const float4*>(xl);
    const float4* w4  = reinterpret_cast<const float4*>(wll);
    float4* o4 = reinterpret_cast<float4*>(out);
#pragma unroll
    for (int j = 0; j < 4; ++j) {
      const int i = llb * 1024 + j * 256 + t;
      const float4 x = xi4[i];
      const float4 w = w4[i % 25088];
      float4 r; r.x = x.x * w.x; r.y = x.y * w.y; r.z = x.z * w.z; r.w = x.w * w.w;
      o4[i] = r;
    }
    return;
  }

  const int mt  = bi % 392;
  const int snb = bi / 392;
  const int ori = snb >> 2;
  const int nb  = snb & 3;
  const int p0 = mt << 7;                    // 128 positions per tile

  char* XB = reinterpret_cast<char*>(Xs);
  const char* WB = reinterpret_cast<const char*>(Ws);
  const float* xb = xh + (size_t)(nb * 32) * 9408 + ori * 1568;
  float* ob = out + 6422528 + (size_t)(nb * 32) * 9408 + ori * 1568;

  // ================= ISSUE PHASE: all global loads batched, no LDS writes =================
  // thread t: position pair p=2*(t&63),p+1; channels (t>>6)*8 .. +7
  // each wave load instruction = 64 lanes x 16B = 1KB contiguous segment
  f32x4 R[8];
  const int pp = t & 63;
  const int cb = (t >> 6) * 8;               // wave-constant channel base
  {
    const int P = p0 + 2 * pp;
    const int bb = P / 784;
    const int hw = P - bb * 784;             // even; P,P+1 share bb
    const float* s = xb + (size_t)bb * 1204224 + (size_t)cb * 9408 + hw * 2;
#pragma unroll
    for (int j = 0; j < 8; ++j)
      R[j] = *reinterpret_cast<const f32x4*>(s + (size_t)j * 9408);  // re(p),im(p),re(p+1),im(p+1)
  }
  uint4 Wr[4];                               // weight image chunks
  float Bv = 0.f;
  {
    const uint4* src = reinterpret_cast<const uint4*>(wg + nb * 8192);
#pragma unroll
    for (int it = 0; it < 4; ++it) Wr[it] = src[it * 256 + t];
  }
  if (t < 128) {
    const int layer = t >> 6, n = t & 63;
    const float* bsrc = layer ? b2 : b1;
    Bv = bsrc[((n >> 5) * 4 + nb) * 32 + (n & 31)];
  }
  __builtin_amdgcn_sched_barrier(0);         // loads stay ABOVE all LDS writes

  // ================= DRAIN PHASE: convert + LDS writes =================
  {
    uint4* dst = reinterpret_cast<uint4*>(Ws);
#pragma unroll
    for (int it = 0; it < 4; ++it) dst[it * 256 + t] = Wr[it];
  }
  if (t < 128) Bs[t] = Bv;
  // pack rows p=2*pp, p+1: re -> group gr=cb/8, im -> gr+4; slot = g ^ s0, s0=pp&7
  {
    const int p = 2 * pp;
    const int s0 = pp & 7;
    const int gr = t >> 6;
    char* row0 = XB + p * 128;
    char* row1 = row0 + 128;
    uint4 u;
    u.x = pack2(R[0].x, R[1].x);  u.y = pack2(R[2].x, R[3].x);
    u.z = pack2(R[4].x, R[5].x);  u.w = pack2(R[6].x, R[7].x);
    *reinterpret_cast<uint4*>(row0 + ((gr ^ s0) * 16)) = u;            // row p, re
    u.x = pack2(R[0].y, R[1].y);  u.y = pack2(R[2].y, R[3].y);
    u.z = pack2(R[4].y, R[5].y);  u.w = pack2(R[6].y, R[7].y);
    *reinterpret_cast<uint4*>(row0 + (((gr + 4) ^ s0) * 16)) = u;      // row p, im
    u.x = pack2(R[0].z, R[1].z);  u.y = pack2(R[2].z, R[3].z);
    u.z = pack2(R[4].z, R[5].z);  u.w = pack2(R[6].z, R[7].z);
    *reinterpret_cast<uint4*>(row1 + ((gr ^ s0) * 16)) = u;            // row p+1, re
    u.x = pack2(R[0].w, R[1].w);  u.y = pack2(R[2].w, R[3].w);
    u.z = pack2(R[4].w, R[5].w);  u.w = pack2(R[6].w, R[7].w);
    *reinterpret_cast<uint4*>(row1 + (((gr + 4) ^ s0) * 16)) = u;      // row p+1, im
  }
  __syncthreads();

  const int lane = t & 63;
  const int wv = t >> 6;                     // wave owns positions [wv*32, wv*32+32)
  const int lr = lane & 15;
  const int lg = lane >> 4;

  // ---- layer 1: D1[n][p] = W1t * X^T ----
  f32x4 acc[4][2];
#pragma unroll
  for (int mi = 0; mi < 4; ++mi)
#pragma unroll
    for (int ni = 0; ni < 2; ++ni)
      acc[mi][ni] = (f32x4){0.f, 0.f, 0.f, 0.f};

#pragma unroll
  for (int ks = 0; ks < 2; ++ks) {
    bf16x8 wf[4], xf[2];
#pragma unroll
    for (int mi = 0; mi < 4; ++mi) {
      const int n = mi * 16 + lr;
      wf[mi] = *reinterpret_cast<const bf16x8*>(WB + n * 128 + (((ks * 4 + lg) ^ ((n >> 1) & 7)) * 16));
    }
#pragma unroll
    for (int ni = 0; ni < 2; ++ni) {
      const int p = wv * 32 + ni * 16 + lr;
      xf[ni] = *reinterpret_cast<const bf16x8*>(XB + p * 128 + (((ks * 4 + lg) ^ ((p >> 1) & 7)) * 16));
    }
#pragma unroll
    for (int mi = 0; mi < 4; ++mi)
#pragma unroll
      for (int ni = 0; ni < 2; ++ni)
        acc[mi][ni] = __builtin_amdgcn_mfma_f32_16x16x32_bf16(wf[mi], xf[ni], acc[mi][ni], 0, 0, 0);
  }

  // ---- ep1: H = relu(D1 + b1) -> back into Xs (wave-private rows, no barrier) ----
#pragma unroll
  for (int mi = 0; mi < 4; ++mi) {
    const f32x4 bv = *reinterpret_cast<const f32x4*>(&Bs[mi * 16 + lg * 4]);
    const int gH = mi * 2 + (lg >> 1);
    const int offH = (lg & 1) * 8;
#pragma unroll
    for (int ni = 0; ni < 2; ++ni) {
      const int p = wv * 32 + ni * 16 + lr;
      const float h0 = fmaxf(acc[mi][ni][0] + bv[0], 0.f);
      const float h1 = fmaxf(acc[mi][ni][1] + bv[1], 0.f);
      const float h2 = fmaxf(acc[mi][ni][2] + bv[2], 0.f);
      const float h3 = fmaxf(acc[mi][ni][3] + bv[3], 0.f);
      uint2 u; u.x = pack2(h0, h1); u.y = pack2(h2, h3);
      *reinterpret_cast<uint2*>(XB + p * 128 + ((gH ^ ((p >> 1) & 7)) * 16) + offH) = u;
    }
  }

  // ---- layer 2: D2[n][p] = W2t * H^T (wave-private rows) ----
  f32x4 acc2[4][2];
#pragma unroll
  for (int mi = 0; mi < 4; ++mi)
#pragma unroll
    for (int ni = 0; ni < 2; ++ni)
      acc2[mi][ni] = (f32x4){0.f, 0.f, 0.f, 0.f};

#pragma unroll
  for (int ks = 0; ks < 2; ++ks) {
    bf16x8 wf[4], hf[2];
#pragma unroll
    for (int mi = 0; mi < 4; ++mi) {
      const int n = mi * 16 + lr;
      wf[mi] = *reinterpret_cast<const bf16x8*>(WB + 8192 + n * 128 + (((ks * 4 + lg) ^ ((n >> 1) & 7)) * 16));
    }
#pragma unroll
    for (int ni = 0; ni < 2; ++ni) {
      const int p = wv * 32 + ni * 16 + lr;
      hf[ni] = *reinterpret_cast<const bf16x8*>(XB + p * 128 + (((ks * 4 + lg) ^ ((p >> 1) & 7)) * 16));
    }
#pragma unroll
    for (int mi = 0; mi < 4; ++mi)
#pragma unroll
      for (int ni = 0; ni < 2; ++ni)
        acc2[mi][ni] = __builtin_amdgcn_mfma_f32_16x16x32_bf16(wf[mi], hf[ni], acc2[mi][ni], 0, 0, 0);
  }

  // ---- ep2: out = D2 + b2, interleaved (re,im) float2 stores ----
#pragma unroll
  for (int ni = 0; ni < 2; ++ni) {
    const int p = wv * 32 + ni * 16 + lr;
    const int P = p0 + p;
    const int bb = P / 784;
    const int hw = P - bb * 784;
    float* obase = ob + (size_t)bb * 1204224 + hw * 2;
#pragma unroll
    for (int mi = 0; mi < 2; ++mi) {
      const f32x4 bre = *reinterpret_cast<const f32x4*>(&Bs[64 + mi * 16 + lg * 4]);
      const f32x4 bim = *reinterpret_cast<const f32x4*>(&Bs[64 + (mi + 2) * 16 + lg * 4]);
#pragma unroll
      for (int j = 0; j < 4; ++j) {
        const int c = mi * 16 + lg * 4 + j;
        float2 v;
        v.x = acc2[mi][ni][j] + bre[j];
        v.y = acc2[mi + 2][ni][j] + bim[j];
        *reinterpret_cast<float2*>(obase + (size_t)c * 9408) = v;
      }
    }
  }
}

extern "C" void kernel_launch(void* const* d_in, const int* in_sizes, int n_in,
                              void* d_out, int out_size, void* d_ws, size_t ws_size,
                              hipStream_t stream) {
  (void)in_sizes; (void)n_in; (void)out_size; (void)ws_size;
  const float* xl  = (const float*)d_in[0];
  const float* xh  = (const float*)d_in[1];
  const float* wll = (const float*)d_in[2];
  const float* w1  = (const float*)d_in[3];
  const float* w2  = (const float*)d_in[4];
  const float* b1  = (const float*)d_in[5];
  const float* b2  = (const float*)d_in[6];
  float* out = (float*)d_out;
  unsigned short* wg = (unsigned short*)d_ws;   // 65536 bytes used

  prep_weights<<<128, 256, 0, stream>>>(w1, w2, wg);
  fused_kernel<<<10976, 256, 0, stream>>>(xh, wg, b1, b2, xl, wll, out);
}